// Round 1
// baseline (1083.154 us; speedup 1.0000x reference)
//
#include <hip/hip_runtime.h>
#include <cstdint>
#include <cstddef>

// ---------------------------------------------------------------------------
// AttentionLayer: s = BN(self@W+b); n = BN(neigh@W+b);
// logits = relu([s,n]@W_out + b_out); coeff = softmax_K(logits)
// Algebraic collapse: logit[i,k] = self[i]·v1 + neigh[i,k]·v2 + C
//   v1 = W @ (inv_s*gamma*w1), v2 = W @ (inv_n*gamma*w2)
//   C  = sum_a(beta*w1 - meandot_s*g1) + sum_a(beta*w2 - meandot_n*g2) + b_out
// (b_shared cancels in BN.)  Only global work: column mean/var of X@W.
// ---------------------------------------------------------------------------

typedef __attribute__((ext_vector_type(8))) short short8;   // 8 bf16 (4 VGPRs)
typedef __attribute__((ext_vector_type(4))) float float4v;  // MFMA C/D frag

__device__ __forceinline__ unsigned short f2bf(float f) {
  union { float f; unsigned u; } v; v.f = f;
  unsigned r = v.u + 0x7FFFu + ((v.u >> 16) & 1u);  // RNE
  return (unsigned short)(r >> 16);
}

// W [256,128] fp32 row-major -> Wt [128][256] bf16 (B^T layout for MFMA B-frags)
__global__ __launch_bounds__(256) void transpose_w(const float* __restrict__ W,
                                                   unsigned short* __restrict__ Wt) {
  const int n = blockIdx.x;    // 0..127 (output col a)
  const int k = threadIdx.x;   // 0..255 (feature f)
  Wt[n * 256 + k] = f2bf(W[k * 128 + n]);
}

// ---------------------------------------------------------------------------
// Stats GEMM: per-column sum and sum-of-squares of X@W (dot only, no bias).
// X: [R,256] fp32. Tile: 128 rows x 128 cols x K-chunks of 32, bf16 MFMA
// 16x16x32.  4 waves = 2x2, each wave 64x64 (4x4 frags).
// Per-block partials: partials[bid*256 + c] (c<128 sum, c>=128 sumsq).
// ---------------------------------------------------------------------------
#define BM 128
#define APAD 40  // 32 + 8 bf16: 80B row stride -> conflict-free ds_read_b128

__global__ __launch_bounds__(256) void stats_gemm(
    const float* __restrict__ X, int R, int nTiles,
    const unsigned short* __restrict__ Wt, float* __restrict__ partials) {
  __shared__ __align__(16) unsigned short As[BM * APAD];
  __shared__ __align__(16) unsigned short Bs[128 * APAD];
  __shared__ float csum[128];
  __shared__ float csq[128];

  const int tid  = threadIdx.x;
  const int lane = tid & 63;
  const int wv   = tid >> 6;
  const int waveM = wv >> 1;   // row half
  const int waveN = wv & 1;    // col half
  const int quad  = lane >> 4;
  const int l16   = lane & 15;

  float runsum = 0.f, runsq = 0.f;

  for (int t = blockIdx.x; t < nTiles; t += gridDim.x) {
    const int row0 = t * BM;
    float4v acc[4][4];
#pragma unroll
    for (int rb = 0; rb < 4; ++rb)
#pragma unroll
      for (int cb = 0; cb < 4; ++cb)
        acc[rb][cb] = (float4v){0.f, 0.f, 0.f, 0.f};

    for (int kc = 0; kc < 8; ++kc) {
      __syncthreads();  // previous chunk's frag reads done before overwrite
      // stage A: 128 rows x 32 f, fp32 -> bf16
#pragma unroll
      for (int it = 0; it < 4; ++it) {
        int idx = it * 256 + tid;
        int r = idx >> 3, j = idx & 7;
        float4 v = make_float4(0.f, 0.f, 0.f, 0.f);
        int gr = row0 + r;
        if (gr < R) v = *(const float4*)(X + (size_t)gr * 256 + kc * 32 + j * 4);
        uint2 p;
        p.x = (unsigned)f2bf(v.x) | ((unsigned)f2bf(v.y) << 16);
        p.y = (unsigned)f2bf(v.z) | ((unsigned)f2bf(v.w) << 16);
        *(uint2*)&As[r * APAD + j * 4] = p;
      }
      // stage B: Wt rows n, k-chunk slice (already bf16, direct copy)
#pragma unroll
      for (int it = 0; it < 4; ++it) {
        int idx = it * 256 + tid;
        int n = idx >> 3, j = idx & 7;
        *(uint2*)&Bs[n * APAD + j * 4] =
            *(const uint2*)(Wt + n * 256 + kc * 32 + j * 4);
      }
      __syncthreads();

      short8 a[4], b[4];
#pragma unroll
      for (int rb = 0; rb < 4; ++rb)
        a[rb] = *(const short8*)&As[(waveM * 64 + rb * 16 + l16) * APAD + quad * 8];
#pragma unroll
      for (int cb = 0; cb < 4; ++cb)
        b[cb] = *(const short8*)&Bs[(waveN * 64 + cb * 16 + l16) * APAD + quad * 8];
#pragma unroll
      for (int rb = 0; rb < 4; ++rb)
#pragma unroll
        for (int cb = 0; cb < 4; ++cb)
          acc[rb][cb] = __builtin_amdgcn_mfma_f32_16x16x32_bf16(
              a[rb], b[cb], acc[rb][cb], 0, 0, 0);
    }

    __syncthreads();
    // Column reduction.  C/D layout: col = lane&15, row = quad*4 + reg.
    float ps[4], pq[4];
#pragma unroll
    for (int cb = 0; cb < 4; ++cb) {
      float s = 0.f, q = 0.f;
#pragma unroll
      for (int rb = 0; rb < 4; ++rb) {
#pragma unroll
        for (int rg = 0; rg < 4; ++rg) {
          int grow = row0 + waveM * 64 + rb * 16 + quad * 4 + rg;
          float x = acc[rb][cb][rg];
          x = (grow < R) ? x : 0.f;
          s += x;
          q += x * x;
        }
      }
      s += __shfl_xor(s, 16); s += __shfl_xor(s, 32);
      q += __shfl_xor(q, 16); q += __shfl_xor(q, 32);
      ps[cb] = s; pq[cb] = q;
    }
    // phase 1: waveM==0 writes; phase 2: waveM==1 adds (disjoint cols per wave)
    if (waveM == 0 && quad == 0) {
#pragma unroll
      for (int cb = 0; cb < 4; ++cb) {
        int col = waveN * 64 + cb * 16 + l16;
        csum[col] = ps[cb];
        csq[col]  = pq[cb];
      }
    }
    __syncthreads();
    if (waveM == 1 && quad == 0) {
#pragma unroll
      for (int cb = 0; cb < 4; ++cb) {
        int col = waveN * 64 + cb * 16 + l16;
        csum[col] += ps[cb];
        csq[col]  += pq[cb];
      }
    }
    __syncthreads();
    if (tid < 128) runsum += csum[tid];
    else           runsq  += csq[tid - 128];
    // next tile's csum write is separated by the chunk-loop barriers
  }
  partials[blockIdx.x * 256 + tid] = (tid < 128) ? runsum : runsq;
}

// stats[0..255] = self (sum|sumsq), stats[256..511] = neigh
__global__ __launch_bounds__(256) void reduce_partials(
    const float* __restrict__ ps, int ns, const float* __restrict__ pn, int nn,
    float* __restrict__ stats) {
  __shared__ float buf[256];
  const int c = blockIdx.x;    // 0..255
  const int tid = threadIdx.x;
  float a = 0.f;
  for (int g = tid; g < ns; g += 256) a += ps[(size_t)g * 256 + c];
  buf[tid] = a;
  __syncthreads();
  for (int s = 128; s > 0; s >>= 1) {
    if (tid < s) buf[tid] += buf[tid + s];
    __syncthreads();
  }
  if (tid == 0) stats[c] = buf[0];
  float b = 0.f;
  for (int g = tid; g < nn; g += 256) b += pn[(size_t)g * 256 + c];
  __syncthreads();
  buf[tid] = b;
  __syncthreads();
  for (int s = 128; s > 0; s >>= 1) {
    if (tid < s) buf[tid] += buf[tid + s];
    __syncthreads();
  }
  if (tid == 0) stats[256 + c] = buf[0];
}

// one block: fold BN + Dense(2A->1) into v1[256], v2[256], C
__global__ __launch_bounds__(256) void setup_kernel(
    const float* __restrict__ stats, const float* __restrict__ W,
    const float* __restrict__ gamma, const float* __restrict__ beta,
    const float* __restrict__ Wout, const float* __restrict__ bout,
    float* __restrict__ v1, float* __restrict__ v2, float* __restrict__ Cout) {
  __shared__ float g1[128], g2[128], carr[128];
  const int tid = threadIdx.x;
  if (tid < 128) {
    const float invNs = 1.f / 20000.f, invNn = 1.f / 640000.f;
    float ms = stats[tid] * invNs;                       // mean of dot (self)
    float vs = stats[128 + tid] * invNs - ms * ms;       // var (b cancels)
    float is = rsqrtf(vs + 1e-3f);
    float mn = stats[256 + tid] * invNn;
    float vn = stats[384 + tid] * invNn - mn * mn;
    float in_ = rsqrtf(vn + 1e-3f);
    float w1 = Wout[tid], w2 = Wout[128 + tid];
    float G1 = is * gamma[tid] * w1;
    float G2 = in_ * gamma[tid] * w2;
    g1[tid] = G1;
    g2[tid] = G2;
    carr[tid] = beta[tid] * (w1 + w2) - ms * G1 - mn * G2;
  }
  __syncthreads();
  float s1 = 0.f, s2 = 0.f;
  const float* wr = W + tid * 128;  // W[f][a], f = tid
  for (int a = 0; a < 128; ++a) {
    float w = wr[a];
    s1 += w * g1[a];
    s2 += w * g2[a];
  }
  v1[tid] = s1;
  v2[tid] = s2;
  if (tid == 0) {
    float c = bout[0];
    for (int a = 0; a < 128; ++a) c += carr[a];
    Cout[0] = c;
  }
}

// one wave per row i: self dot + 32 neighbor dots + in-wave softmax. No LDS.
__global__ __launch_bounds__(256) void attn_final(
    const float* __restrict__ self, const float* __restrict__ neigh,
    const float* __restrict__ v1, const float* __restrict__ v2,
    const float* __restrict__ Cptr, float* __restrict__ out) {
  const int lane = threadIdx.x & 63;
  const int wv = threadIdx.x >> 6;
  const int i = blockIdx.x * 4 + wv;  // 5000*4 = 20000 exact
  const float C = Cptr[0];
  const float4 w1v = *(const float4*)(v1 + lane * 4);
  const float4 w2v = *(const float4*)(v2 + lane * 4);

  float4 sv = *(const float4*)(self + (size_t)i * 256 + lane * 4);
  float sd = fmaf(sv.x, w1v.x, fmaf(sv.y, w1v.y, fmaf(sv.z, w1v.z, sv.w * w1v.w)));
#pragma unroll
  for (int m = 32; m >= 1; m >>= 1) sd += __shfl_xor(sd, m);

  const float4* np = (const float4*)(neigh + (size_t)i * 8192);
  float ml = 0.f;
#pragma unroll 4
  for (int k = 0; k < 32; ++k) {
    float4 nv = np[k * 64 + lane];  // 1 KiB coalesced per neighbor
    float nd = fmaf(nv.x, w2v.x, fmaf(nv.y, w2v.y, fmaf(nv.z, w2v.z, nv.w * w2v.w)));
#pragma unroll
    for (int m = 32; m >= 1; m >>= 1) nd += __shfl_xor(nd, m);
    if ((lane & 31) == k) ml = nd;  // both 32-lane halves hold the full set
  }
  float logit = fmaxf(ml + sd + C, 0.f);
  float mx = logit;
#pragma unroll
  for (int m = 16; m >= 1; m >>= 1) mx = fmaxf(mx, __shfl_xor(mx, m));
  float e = __expf(logit - mx);
  float ssum = e;
#pragma unroll
  for (int m = 16; m >= 1; m >>= 1) ssum += __shfl_xor(ssum, m);
  if (lane < 32) out[(size_t)i * 32 + lane] = e / ssum;
}

extern "C" void kernel_launch(void* const* d_in, const int* in_sizes, int n_in,
                              void* d_out, int out_size, void* d_ws, size_t ws_size,
                              hipStream_t stream) {
  const float* self  = (const float*)d_in[0];  // [20000,256]
  const float* neigh = (const float*)d_in[1];  // [20000,32,256]
  const float* W     = (const float*)d_in[2];  // [256,128]
  // d_in[3] = b_shared: cancels in BN, unused
  const float* gamma = (const float*)d_in[4];
  const float* beta  = (const float*)d_in[5];
  const float* Wout  = (const float*)d_in[6];  // [256,1]
  const float* bout  = (const float*)d_in[7];
  float* out = (float*)d_out;

  // workspace layout (~1.28 MB)
  char* ws = (char*)d_ws;
  unsigned short* Wt = (unsigned short*)ws;            // 128*256 bf16 = 64 KiB
  float* part_s = (float*)(ws + 65536);                // 157*256
  float* part_n = part_s + 157 * 256;                  // 1024*256
  float* stats  = part_n + 1024 * 256;                 // 512
  float* v1     = stats + 512;                         // 256
  float* v2     = v1 + 256;                            // 256
  float* Cc     = v2 + 256;                            // 1

  hipLaunchKernelGGL(transpose_w, dim3(128), dim3(256), 0, stream, W, Wt);
  hipLaunchKernelGGL(stats_gemm, dim3(157), dim3(256), 0, stream,
                     self, 20000, 157, Wt, part_s);
  hipLaunchKernelGGL(stats_gemm, dim3(1024), dim3(256), 0, stream,
                     neigh, 640000, 5000, Wt, part_n);
  hipLaunchKernelGGL(reduce_partials, dim3(256), dim3(256), 0, stream,
                     part_s, 157, part_n, 1024, stats);
  hipLaunchKernelGGL(setup_kernel, dim3(1), dim3(256), 0, stream,
                     stats, W, gamma, beta, Wout, bout, v1, v2, Cc);
  hipLaunchKernelGGL(attn_final, dim3(5000), dim3(256), 0, stream,
                     self, neigh, v1, v2, Cc, out);
}

// Round 2
// 1033.008 us; speedup vs baseline: 1.0485x; 1.0485x over previous
//
#include <hip/hip_runtime.h>
#include <cstdint>
#include <cstddef>

// ---------------------------------------------------------------------------
// AttentionLayer collapse: logit[i,k] = sum_a G1[a]*u_s[i,a] + G2[a]*u_n[i,k,a] + C
// where u = X@W (bf16 MFMA product, also stored for pass 2),
// G1 = inv_s*gamma*w1, G2 = inv_n*gamma*w2,
// C  = b_out + sum_a beta*(w1+w2) - ms*G1 - mn*G2.  (b_shared cancels in BN.)
// Pass 1 computes u + column sum/sumsq; pass 2 reads bf16 u only (4x smaller).
// ---------------------------------------------------------------------------

typedef __attribute__((ext_vector_type(8))) short short8;   // 8 bf16 (4 VGPRs)
typedef __attribute__((ext_vector_type(4))) float float4v;  // MFMA C/D frag

__device__ __forceinline__ unsigned short f2bf(float f) {
  union { float f; unsigned u; } v; v.f = f;
  unsigned r = v.u + 0x7FFFu + ((v.u >> 16) & 1u);  // RNE
  return (unsigned short)(r >> 16);
}
__device__ __forceinline__ float bfu(unsigned v) {  // low 16 bits -> float
  union { unsigned u; float f; } t; t.u = v << 16; return t.f;
}

// W [256,128] fp32 row-major -> Wt [128][256] bf16 (B^T layout for MFMA B-frags)
__global__ __launch_bounds__(256) void transpose_w(const float* __restrict__ W,
                                                   unsigned short* __restrict__ Wt) {
  const int n = blockIdx.x;    // 0..127 (output col a)
  const int k = threadIdx.x;   // 0..255 (feature f)
  Wt[n * 256 + k] = f2bf(W[k * 128 + n]);
}

// ---------------------------------------------------------------------------
// Stats GEMM: u = X@W (stored bf16) + per-column sum / sumsq of u.
// X: [R,256] fp32. Tile 128x128, K-chunks of 32, bf16 MFMA 16x16x32,
// 4 waves = 2x2, each wave 64x64 (4x4 frags).
// partials[bid*256 + c]: c<128 sum, c>=128 sumsq.
// ---------------------------------------------------------------------------
#define BM 128
#define APAD 40  // 32 + 8 bf16: 80B row stride -> conflict-free ds_read_b128

__global__ __launch_bounds__(256) void stats_gemm(
    const float* __restrict__ X, int R, int nTiles,
    const unsigned short* __restrict__ Wt,
    unsigned short* __restrict__ U,          // [R,128] bf16 out
    float* __restrict__ partials) {
  __shared__ __align__(16) unsigned short As[BM * APAD];
  __shared__ __align__(16) unsigned short Bs[128 * APAD];
  __shared__ float csum[128];
  __shared__ float csq[128];

  const int tid  = threadIdx.x;
  const int lane = tid & 63;
  const int wv   = tid >> 6;
  const int waveM = wv >> 1;   // row half
  const int waveN = wv & 1;    // col half
  const int quad  = lane >> 4;
  const int l16   = lane & 15;

  float runsum = 0.f, runsq = 0.f;

  for (int t = blockIdx.x; t < nTiles; t += gridDim.x) {
    const int row0 = t * BM;
    float4v acc[4][4];
#pragma unroll
    for (int rb = 0; rb < 4; ++rb)
#pragma unroll
      for (int cb = 0; cb < 4; ++cb)
        acc[rb][cb] = (float4v){0.f, 0.f, 0.f, 0.f};

    for (int kc = 0; kc < 8; ++kc) {
      __syncthreads();  // previous chunk's frag reads done before overwrite
      // stage A: 128 rows x 32 f, fp32 -> bf16
#pragma unroll
      for (int it = 0; it < 4; ++it) {
        int idx = it * 256 + tid;
        int r = idx >> 3, j = idx & 7;
        float4 v = make_float4(0.f, 0.f, 0.f, 0.f);
        int gr = row0 + r;
        if (gr < R) v = *(const float4*)(X + (size_t)gr * 256 + kc * 32 + j * 4);
        uint2 p;
        p.x = (unsigned)f2bf(v.x) | ((unsigned)f2bf(v.y) << 16);
        p.y = (unsigned)f2bf(v.z) | ((unsigned)f2bf(v.w) << 16);
        *(uint2*)&As[r * APAD + j * 4] = p;
      }
      // stage B: Wt rows n, k-chunk slice (already bf16, direct copy)
#pragma unroll
      for (int it = 0; it < 4; ++it) {
        int idx = it * 256 + tid;
        int n = idx >> 3, j = idx & 7;
        *(uint2*)&Bs[n * APAD + j * 4] =
            *(const uint2*)(Wt + n * 256 + kc * 32 + j * 4);
      }
      __syncthreads();

      short8 a[4], b[4];
#pragma unroll
      for (int rb = 0; rb < 4; ++rb)
        a[rb] = *(const short8*)&As[(waveM * 64 + rb * 16 + l16) * APAD + quad * 8];
#pragma unroll
      for (int cb = 0; cb < 4; ++cb)
        b[cb] = *(const short8*)&Bs[(waveN * 64 + cb * 16 + l16) * APAD + quad * 8];
#pragma unroll
      for (int rb = 0; rb < 4; ++rb)
#pragma unroll
        for (int cb = 0; cb < 4; ++cb)
          acc[rb][cb] = __builtin_amdgcn_mfma_f32_16x16x32_bf16(
              a[rb], b[cb], acc[rb][cb], 0, 0, 0);
    }

    __syncthreads();
    // Store u (bf16) + column reduction. C/D layout: col=lane&15, row=quad*4+reg.
    float ps[4], pq[4];
#pragma unroll
    for (int cb = 0; cb < 4; ++cb) {
      const int col = waveN * 64 + cb * 16 + l16;
      float s = 0.f, q = 0.f;
#pragma unroll
      for (int rb = 0; rb < 4; ++rb) {
#pragma unroll
        for (int rg = 0; rg < 4; ++rg) {
          int grow = row0 + waveM * 64 + rb * 16 + quad * 4 + rg;
          float x = acc[rb][cb][rg];
          if (grow < R) {
            U[(size_t)grow * 128 + col] = f2bf(x);
            s += x;
            q += x * x;
          }
        }
      }
      s += __shfl_xor(s, 16); s += __shfl_xor(s, 32);
      q += __shfl_xor(q, 16); q += __shfl_xor(q, 32);
      ps[cb] = s; pq[cb] = q;
    }
    // phase 1: waveM==0 writes; phase 2: waveM==1 adds (disjoint cols per wave)
    if (waveM == 0 && quad == 0) {
#pragma unroll
      for (int cb = 0; cb < 4; ++cb) {
        int col = waveN * 64 + cb * 16 + l16;
        csum[col] = ps[cb];
        csq[col]  = pq[cb];
      }
    }
    __syncthreads();
    if (waveM == 1 && quad == 0) {
#pragma unroll
      for (int cb = 0; cb < 4; ++cb) {
        int col = waveN * 64 + cb * 16 + l16;
        csum[col] += ps[cb];
        csq[col]  += pq[cb];
      }
    }
    __syncthreads();
    if (tid < 128) runsum += csum[tid];
    else           runsq  += csq[tid - 128];
  }
  partials[blockIdx.x * 256 + tid] = (tid < 128) ? runsum : runsq;
}

// stats[0..255] = self (sum|sumsq), stats[256..511] = neigh
__global__ __launch_bounds__(256) void reduce_partials(
    const float* __restrict__ ps, int ns, const float* __restrict__ pn, int nn,
    float* __restrict__ stats) {
  __shared__ float buf[256];
  const int c = blockIdx.x;    // 0..255
  const int tid = threadIdx.x;
  float a = 0.f;
  for (int g = tid; g < ns; g += 256) a += ps[(size_t)g * 256 + c];
  buf[tid] = a;
  __syncthreads();
  for (int s = 128; s > 0; s >>= 1) {
    if (tid < s) buf[tid] += buf[tid + s];
    __syncthreads();
  }
  if (tid == 0) stats[c] = buf[0];
  float b = 0.f;
  for (int g = tid; g < nn; g += 256) b += pn[(size_t)g * 256 + c];
  __syncthreads();
  buf[tid] = b;
  __syncthreads();
  for (int s = 128; s > 0; s >>= 1) {
    if (tid < s) buf[tid] += buf[tid + s];
    __syncthreads();
  }
  if (tid == 0) stats[256 + c] = buf[0];
}

// one block: fold BN + Dense(2A->1) into G1[128], G2[128], C
__global__ __launch_bounds__(128) void setup_kernel(
    const float* __restrict__ stats,
    const float* __restrict__ gamma, const float* __restrict__ beta,
    const float* __restrict__ Wout, const float* __restrict__ bout,
    float* __restrict__ G1, float* __restrict__ G2, float* __restrict__ Cout) {
  __shared__ float carr[128];
  const int tid = threadIdx.x;
  const float invNs = 1.f / 20000.f, invNn = 1.f / 640000.f;
  float ms = stats[tid] * invNs;                       // mean of dot (self)
  float vs = stats[128 + tid] * invNs - ms * ms;       // var (b cancels)
  float is = rsqrtf(vs + 1e-3f);
  float mn = stats[256 + tid] * invNn;
  float vn = stats[384 + tid] * invNn - mn * mn;
  float in_ = rsqrtf(vn + 1e-3f);
  float w1 = Wout[tid], w2 = Wout[128 + tid];
  float g1 = is * gamma[tid] * w1;
  float g2 = in_ * gamma[tid] * w2;
  G1[tid] = g1;
  G2[tid] = g2;
  carr[tid] = beta[tid] * (w1 + w2) - ms * g1 - mn * g2;
  __syncthreads();
  if (tid == 0) {
    float c = bout[0];
    for (int a = 0; a < 128; ++a) c += carr[a];
    Cout[0] = c;
  }
}

// one wave per row i: dots against bf16 u + in-wave softmax. No LDS.
__global__ __launch_bounds__(256) void attn_final(
    const unsigned short* __restrict__ Us,   // [20000,128] bf16
    const unsigned short* __restrict__ Un,   // [640000,128] bf16
    const float* __restrict__ G1, const float* __restrict__ G2,
    const float* __restrict__ Cptr, float* __restrict__ out) {
  const int lane = threadIdx.x & 63;
  const int wv = threadIdx.x >> 6;
  const int i = blockIdx.x * 4 + wv;  // 5000*4 = 20000 exact
  const int l16 = lane & 15;
  const int l32 = lane & 31;
  const int quarter = lane >> 4;      // 0..3
  const float C = Cptr[0];

  // self: lane handles elems 2*lane, 2*lane+1
  unsigned su = *(const unsigned*)(Us + (size_t)i * 128 + lane * 2);
  float2 g1p = *(const float2*)(G1 + lane * 2);
  float sd = fmaf(g1p.x, bfu(su), g1p.y * bfu(su >> 16));
#pragma unroll
  for (int m = 32; m >= 1; m >>= 1) sd += __shfl_xor(sd, m);

  // neighbors: 4 per iteration; quarter q handles neighbor 4j+q,
  // lane covers elems l16*8..l16*8+7 (uint4 = 8 bf16 = 16B, wave reads 1KiB).
  const float4 ga = *(const float4*)(G2 + l16 * 8);
  const float4 gb = *(const float4*)(G2 + l16 * 8 + 4);
  const unsigned short* un = Un + (size_t)i * 4096;
  float ml = 0.f;
#pragma unroll
  for (int j = 0; j < 8; ++j) {
    const int nb = j * 4 + quarter;
    uint4 q = *(const uint4*)(un + nb * 128 + l16 * 8);
    float p;
    p = fmaf(ga.x, bfu(q.x), ga.y * bfu(q.x >> 16));
    p = fmaf(ga.z, bfu(q.y), p); p = fmaf(ga.w, bfu(q.y >> 16), p);
    p = fmaf(gb.x, bfu(q.z), p); p = fmaf(gb.y, bfu(q.z >> 16), p);
    p = fmaf(gb.z, bfu(q.w), p); p = fmaf(gb.w, bfu(q.w >> 16), p);
#pragma unroll
    for (int m = 1; m <= 8; m <<= 1) p += __shfl_xor(p, m);
    // p = dot(4j+quarter) on all 16 lanes of this quarter
    float s16 = __shfl_xor(p, 16);     // dot(4j + quarter^1)
    float s32 = __shfl_xor(p, 32);     // dot(4j + quarter^2)
    float s48 = __shfl_xor(s16, 32);   // dot(4j + quarter^3)
    if ((l32 >> 2) == j) {
      int x = (l32 & 3) ^ quarter;
      ml = (x == 0) ? p : (x == 1) ? s16 : (x == 2) ? s32 : s48;
    }
  }
  float logit = fmaxf(ml + sd + C, 0.f);
  float mx = logit;
#pragma unroll
  for (int m = 16; m >= 1; m >>= 1) mx = fmaxf(mx, __shfl_xor(mx, m));
  float e = __expf(logit - mx);
  float ssum = e;
#pragma unroll
  for (int m = 16; m >= 1; m >>= 1) ssum += __shfl_xor(ssum, m);
  if (lane < 32) out[(size_t)i * 32 + lane] = e / ssum;
}

extern "C" void kernel_launch(void* const* d_in, const int* in_sizes, int n_in,
                              void* d_out, int out_size, void* d_ws, size_t ws_size,
                              hipStream_t stream) {
  const float* self  = (const float*)d_in[0];  // [20000,256]
  const float* neigh = (const float*)d_in[1];  // [20000,32,256]
  const float* W     = (const float*)d_in[2];  // [256,128]
  // d_in[3] = b_shared: cancels in BN, unused
  const float* gamma = (const float*)d_in[4];
  const float* beta  = (const float*)d_in[5];
  const float* Wout  = (const float*)d_in[6];  // [256,1]
  const float* bout  = (const float*)d_in[7];
  float* out = (float*)d_out;

  // workspace layout (~170.3 MB)
  char* ws = (char*)d_ws;
  unsigned short* Wt = (unsigned short*)ws;              // 64 KiB
  unsigned short* Us = (unsigned short*)(ws + (1 << 16));          // 5.12 MB
  unsigned short* Un = Us + (size_t)20000 * 128;                   // 163.84 MB
  float* part_s = (float*)(Un + (size_t)640000 * 128);   // 157*256
  float* part_n = part_s + 157 * 256;                    // 1024*256
  float* stats  = part_n + 1024 * 256;                   // 512
  float* G1     = stats + 512;                           // 128
  float* G2     = G1 + 128;                              // 128
  float* Cc     = G2 + 128;                              // 1

  hipLaunchKernelGGL(transpose_w, dim3(128), dim3(256), 0, stream, W, Wt);
  hipLaunchKernelGGL(stats_gemm, dim3(157), dim3(256), 0, stream,
                     self, 20000, 157, Wt, Us, part_s);
  hipLaunchKernelGGL(stats_gemm, dim3(1024), dim3(256), 0, stream,
                     neigh, 640000, 5000, Wt, Un, part_n);
  hipLaunchKernelGGL(reduce_partials, dim3(256), dim3(256), 0, stream,
                     part_s, 157, part_n, 1024, stats);
  hipLaunchKernelGGL(setup_kernel, dim3(1), dim3(128), 0, stream,
                     stats, gamma, beta, Wout, bout, G1, G2, Cc);
  hipLaunchKernelGGL(attn_final, dim3(5000), dim3(256), 0, stream,
                     Us, Un, G1, G2, Cc, out);
}